// Round 5
// baseline (135.820 us; speedup 1.0000x reference)
//
#include <hip/hip_runtime.h>
#include <math.h>

#define Bsz  2
#define Cch  16
#define Hdim 256
#define Wdim 256
#define HW   (Hdim * Wdim)
#define BHW  (Bsz * HW)
#define CctxN 64
#define NS   8            // g-segments
#define SG   (Hdim / NS)  // 32 g values per segment
#define TH   8            // h rows per block
#define LOG2E 1.44269504088896340736f

// exp2f lowers to v_exp_f32 on amdgcn (HW exp is base-2).
__device__ __forceinline__ float fexp2(float x) { return exp2f(x); }

// Kernel 1: projections. 4 hw per thread, float4 (dwordx4) loads.
// q pre-scaled by log2e. kv packs (k0,k1,v,0) for one-dwordx4 column loads.
__global__ __launch_bounds__(256) void qkv_kernel(
    const float* __restrict__ x, const float* __restrict__ y,
    const float* __restrict__ Wq, const float* __restrict__ bq,
    const float* __restrict__ Wk, const float* __restrict__ bk,
    const float* __restrict__ Wv, const float* __restrict__ bv,
    float2* __restrict__ qpk, float4* __restrict__ kv) {
  int idx0 = (blockIdx.x * blockDim.x + threadIdx.x) * 4;  // b*HW + hw
  int b  = idx0 >> 16;
  int hw = idx0 & (HW - 1);
  const float4* xp = (const float4*)(x + (size_t)b * Cch * HW + hw);
  float q0[4], q1[4], k0[4], k1[4], vv[4];
#pragma unroll
  for (int j = 0; j < 4; j++) { q0[j] = bq[0]; q1[j] = bq[1]; k0[j] = bk[0]; k1[j] = bk[1]; vv[j] = bv[0]; }
#pragma unroll
  for (int c = 0; c < Cch; c++) {
    float4 xv = xp[c * (HW / 4)];
    float wq0 = Wq[c], wq1 = Wq[Cch + c], wk0 = Wk[c], wk1 = Wk[Cch + c];
    const float* xe = (const float*)&xv;
#pragma unroll
    for (int j = 0; j < 4; j++) {
      q0[j] = fmaf(wq0, xe[j], q0[j]);
      q1[j] = fmaf(wq1, xe[j], q1[j]);
      k0[j] = fmaf(wk0, xe[j], k0[j]);
      k1[j] = fmaf(wk1, xe[j], k1[j]);
    }
  }
  const float4* yp = (const float4*)(y + (size_t)b * CctxN * HW + hw);
#pragma unroll
  for (int c = 0; c < CctxN; c++) {
    float4 yv = yp[c * (HW / 4)];
    const float* ye = (const float*)&yv;
    float wv = Wv[c];
#pragma unroll
    for (int j = 0; j < 4; j++) vv[j] = fmaf(wv, ye[j], vv[j]);
  }
  float4* qout = (float4*)&qpk[idx0];   // 4 float2 = 2 float4, contiguous
  qout[0] = make_float4(q0[0] * LOG2E, q1[0] * LOG2E, q0[1] * LOG2E, q1[1] * LOG2E);
  qout[1] = make_float4(q0[2] * LOG2E, q1[2] * LOG2E, q0[3] * LOG2E, q1[3] * LOG2E);
#pragma unroll
  for (int j = 0; j < 4; j++) kv[idx0 + j] = make_float4(k0[j], k1[j], vv[j], 0.f);
}

// Kernel 2: partial criss-cross softmax sums (no max-sub: scores bounded).
// Block = (b, h-tile of TH=8, g-segment of SG=32). Thread = w. Column kv
// loads amortized over 8 h-rows; row kv in LDS (wave-broadcast reads).
// Diagonal handled by post-loop subtraction (no per-iter mask).
__global__ __launch_bounds__(256) void attn_kernel(
    const float2* __restrict__ qpk, const float4* __restrict__ kv,
    float* __restrict__ part) {
  int s  = blockIdx.x & (NS - 1);
  int ht = (blockIdx.x >> 3) & 31;    // Hdim/TH = 32
  int b  = blockIdx.x >> 8;
  int w  = threadIdx.x;
  int h0 = ht * TH;
  int g0 = s * SG;
  size_t bbase = (size_t)b * HW;

  __shared__ float4 rowkv[TH][SG];    // TH*SG == 256: one entry per thread
  {
    int h_l = threadIdx.x >> 5, gg = threadIdx.x & 31;
    rowkv[h_l][gg] = kv[bbase + (size_t)(h0 + h_l) * Wdim + g0 + gg];
  }
  float q0[TH], q1[TH];
#pragma unroll
  for (int h_l = 0; h_l < TH; h_l++) {
    float2 qq = qpk[bbase + (size_t)(h0 + h_l) * Wdim + w];
    q0[h_l] = qq.x; q1[h_l] = qq.y;
  }
  __syncthreads();

  float Z[TH], nH[TH], nW[TH];
#pragma unroll
  for (int h_l = 0; h_l < TH; h_l++) { Z[h_l] = 0.f; nH[h_l] = 0.f; nW[h_l] = 0.f; }
#pragma unroll 2
  for (int gg = 0; gg < SG; gg++) {
    float4 kc = kv[bbase + (size_t)(g0 + gg) * Wdim + w];
#pragma unroll
    for (int h_l = 0; h_l < TH; h_l++) {
      float4 r = rowkv[h_l][gg];
      float pH = fexp2(fmaf(q0[h_l], kc.x, q1[h_l] * kc.y));
      float pW = fexp2(fmaf(q0[h_l], r.x,  q1[h_l] * r.y));
      Z [h_l] += pH + pW;
      nH[h_l] = fmaf(pH, kc.z, nH[h_l]);
      nW[h_l] = fmaf(pW, r.z,  nW[h_l]);
    }
  }
  // Diagonal fixup: h0..h0+7 lies inside one 32-wide segment (8 | 32).
  if ((h0 >> 5) == s) {
#pragma unroll
    for (int h_l = 0; h_l < TH; h_l++) {
      float4 kd = kv[bbase + (size_t)(h0 + h_l) * Wdim + w];
      float pd = fexp2(fmaf(q0[h_l], kd.x, q1[h_l] * kd.y));
      Z [h_l] -= pd;
      nH[h_l] = fmaf(-pd, kd.z, nH[h_l]);
    }
  }
#pragma unroll
  for (int h_l = 0; h_l < TH; h_l++) {
    size_t idx = bbase + (size_t)(h0 + h_l) * Wdim + w;
    part[(size_t)(s * 3 + 0) * BHW + idx] = Z [h_l];
    part[(size_t)(s * 3 + 1) * BHW + idx] = nH[h_l];
    part[(size_t)(s * 3 + 2) * BHW + idx] = nW[h_l];
  }
}

// Kernel 3: merge NS partials, finalize, residual add, broadcast 16 channels.
// 4 hw per thread, float4 traffic throughout.
__global__ __launch_bounds__(256) void epi_kernel(
    const float* __restrict__ x, const float* __restrict__ part,
    const float* __restrict__ gamma, float* __restrict__ out) {
  int idx0 = (blockIdx.x * blockDim.x + threadIdx.x) * 4;
  float Z[4] = {0,0,0,0}, nH[4] = {0,0,0,0}, nW[4] = {0,0,0,0};
#pragma unroll
  for (int s2 = 0; s2 < NS; s2++) {
    float4 a = *(const float4*)&part[(size_t)(s2 * 3 + 0) * BHW + idx0];
    float4 c = *(const float4*)&part[(size_t)(s2 * 3 + 1) * BHW + idx0];
    float4 d = *(const float4*)&part[(size_t)(s2 * 3 + 2) * BHW + idx0];
    const float *ae = (const float*)&a, *ce = (const float*)&c, *de = (const float*)&d;
#pragma unroll
    for (int j = 0; j < 4; j++) { Z[j] += ae[j]; nH[j] += ce[j]; nW[j] += de[j]; }
  }
  float g = gamma[0];
  float sv[4];
#pragma unroll
  for (int j = 0; j < 4; j++) sv[j] = g * (nH[j] + nW[j]) / Z[j];
  int b = idx0 >> 16, hw = idx0 & (HW - 1);
  size_t base = (size_t)b * Cch * HW + hw;
#pragma unroll
  for (int c = 0; c < Cch; c++) {
    float4 xv = *(const float4*)&x[base + c * HW];
    *(float4*)&out[base + c * HW] =
        make_float4(sv[0] + xv.x, sv[1] + xv.y, sv[2] + xv.z, sv[3] + xv.w);
  }
}

extern "C" void kernel_launch(void* const* d_in, const int* in_sizes, int n_in,
                              void* d_out, int out_size, void* d_ws, size_t ws_size,
                              hipStream_t stream) {
  const float* x     = (const float*)d_in[0];
  const float* y     = (const float*)d_in[1];
  const float* Wq    = (const float*)d_in[2];
  const float* bq    = (const float*)d_in[3];
  const float* Wk    = (const float*)d_in[4];
  const float* bk    = (const float*)d_in[5];
  const float* Wv    = (const float*)d_in[6];
  const float* bv    = (const float*)d_in[7];
  const float* gamma = (const float*)d_in[8];
  float* out = (float*)d_out;

  float* ws = (float*)d_ws;
  float2* qpk = (float2*)ws;                  // BHW float2 (1 MB)
  float4* kv  = (float4*)(ws + 2 * BHW);      // BHW float4 (2 MB)
  float*  part = ws + 6 * BHW;                // 3*NS*BHW floats (12.6 MB)

  qkv_kernel<<<BHW / 1024, 256, 0, stream>>>(x, y, Wq, bq, Wk, bk, Wv, bv, qpk, kv);
  attn_kernel<<<Bsz * (Hdim / TH) * NS, 256, 0, stream>>>(qpk, kv, part);
  epi_kernel<<<BHW / 1024, 256, 0, stream>>>(x, part, gamma, out);
}

// Round 6
// 126.605 us; speedup vs baseline: 1.0728x; 1.0728x over previous
//
#include <hip/hip_runtime.h>
#include <math.h>

#define Bsz  2
#define Cch  16
#define Hdim 256
#define Wdim 256
#define HW   (Hdim * Wdim)
#define BHW  (Bsz * HW)
#define CctxN 64
#define NS   4            // g-segments
#define SG   (Hdim / NS)  // 64 g values per segment
#define TH   4            // h rows per block
#define LOG2E 1.44269504088896340736f

// exp2f lowers to v_exp_f32 on amdgcn (HW exp is base-2).
__device__ __forceinline__ float fexp2(float x) { return exp2f(x); }

// Kernel 1: projections. 2 hw per thread, float2 loads. q pre-scaled by log2e.
// kv packs (k0, k1, v, 0) per position for one-dwordx4 column loads in attn.
__global__ __launch_bounds__(256) void qkv_kernel(
    const float* __restrict__ x, const float* __restrict__ y,
    const float* __restrict__ Wq, const float* __restrict__ bq,
    const float* __restrict__ Wk, const float* __restrict__ bk,
    const float* __restrict__ Wv, const float* __restrict__ bv,
    float2* __restrict__ qpk, float4* __restrict__ kv) {
  int idx0 = (blockIdx.x * blockDim.x + threadIdx.x) * 2;  // b*HW + hw, even
  int b  = idx0 >> 16;
  int hw = idx0 & (HW - 1);
  const float2* xp = (const float2*)(x + (size_t)b * Cch * HW + hw);
  float q0a = bq[0], q1a = bq[1], k0a = bk[0], k1a = bk[1];
  float q0b = bq[0], q1b = bq[1], k0b = bk[0], k1b = bk[1];
#pragma unroll
  for (int c = 0; c < Cch; c++) {
    float2 xv = xp[c * (HW / 2)];
    q0a = fmaf(Wq[c],       xv.x, q0a);  q0b = fmaf(Wq[c],       xv.y, q0b);
    q1a = fmaf(Wq[Cch + c], xv.x, q1a);  q1b = fmaf(Wq[Cch + c], xv.y, q1b);
    k0a = fmaf(Wk[c],       xv.x, k0a);  k0b = fmaf(Wk[c],       xv.y, k0b);
    k1a = fmaf(Wk[Cch + c], xv.x, k1a);  k1b = fmaf(Wk[Cch + c], xv.y, k1b);
  }
  qpk[idx0]     = make_float2(q0a * LOG2E, q1a * LOG2E);
  qpk[idx0 + 1] = make_float2(q0b * LOG2E, q1b * LOG2E);
  const float2* yp = (const float2*)(y + (size_t)b * CctxN * HW + hw);
  float va = bv[0], vb2 = bv[0];
#pragma unroll
  for (int c = 0; c < CctxN; c++) {
    float2 yv = yp[c * (HW / 2)];
    va  = fmaf(Wv[c], yv.x, va);
    vb2 = fmaf(Wv[c], yv.y, vb2);
  }
  kv[idx0]     = make_float4(k0a, k1a, va,  0.f);
  kv[idx0 + 1] = make_float4(k0b, k1b, vb2, 0.f);
}

// Kernel 2: partial criss-cross softmax sums (no max-sub: scores bounded).
// Block = (b, h-tile of TH, g-segment of SG). Thread = w. Diagonal handled by
// post-loop subtraction (no per-iter mask). Row kv in LDS (broadcast reads).
// Partials packed (Z, nH, nW, 0) -> single dwordx4 store per (h_l).
__global__ __launch_bounds__(256) void attn_kernel(
    const float2* __restrict__ qpk, const float4* __restrict__ kv,
    float4* __restrict__ part) {
  int s  = blockIdx.x & (NS - 1);
  int ht = (blockIdx.x >> 2) & 63;    // Hdim/TH = 64
  int b  = blockIdx.x >> 8;
  int w  = threadIdx.x;
  int h0 = ht * TH;
  int g0 = s * SG;
  size_t bbase = (size_t)b * HW;

  __shared__ float4 rowkv[TH][SG];
  {
    int h_l = threadIdx.x >> 6, gg = threadIdx.x & 63;  // TH*SG == 256
    rowkv[h_l][gg] = kv[bbase + (size_t)(h0 + h_l) * Wdim + g0 + gg];
  }
  float q0[TH], q1[TH];
#pragma unroll
  for (int h_l = 0; h_l < TH; h_l++) {
    float2 qq = qpk[bbase + (size_t)(h0 + h_l) * Wdim + w];
    q0[h_l] = qq.x; q1[h_l] = qq.y;
  }
  __syncthreads();

  float Z[TH] = {0,0,0,0}, nH[TH] = {0,0,0,0}, nW[TH] = {0,0,0,0};
#pragma unroll 4
  for (int gg = 0; gg < SG; gg++) {
    float4 kc = kv[bbase + (size_t)(g0 + gg) * Wdim + w];
#pragma unroll
    for (int h_l = 0; h_l < TH; h_l++) {
      float4 r = rowkv[h_l][gg];
      float pH = fexp2(fmaf(q0[h_l], kc.x, q1[h_l] * kc.y));
      float pW = fexp2(fmaf(q0[h_l], r.x,  q1[h_l] * r.y));
      Z [h_l] += pH + pW;
      nH[h_l] = fmaf(pH, kc.z, nH[h_l]);
      nW[h_l] = fmaf(pW, r.z,  nW[h_l]);
    }
  }
  // Diagonal fixup: subtract the g==h term (whole h-tile lies in one segment).
  if ((h0 >> 6) == s) {
#pragma unroll
    for (int h_l = 0; h_l < TH; h_l++) {
      float4 kd = kv[bbase + (size_t)(h0 + h_l) * Wdim + w];
      float pd = fexp2(fmaf(q0[h_l], kd.x, q1[h_l] * kd.y));
      Z [h_l] -= pd;
      nH[h_l] = fmaf(-pd, kd.z, nH[h_l]);
    }
  }
#pragma unroll
  for (int h_l = 0; h_l < TH; h_l++) {
    size_t idx = bbase + (size_t)(h0 + h_l) * Wdim + w;
    part[(size_t)s * BHW + idx] = make_float4(Z[h_l], nH[h_l], nW[h_l], 0.f);
  }
}

// Kernel 3: merge NS partials, finalize, residual add, broadcast 16 channels.
// 2 hw per thread; partials read as dwordx4.
__global__ __launch_bounds__(256) void epi_kernel(
    const float* __restrict__ x, const float4* __restrict__ part,
    const float* __restrict__ gamma, float* __restrict__ out) {
  int idx0 = (blockIdx.x * blockDim.x + threadIdx.x) * 2;
  float Za = 0.f, nHa = 0.f, nWa = 0.f;
  float Zb = 0.f, nHb = 0.f, nWb = 0.f;
#pragma unroll
  for (int s2 = 0; s2 < NS; s2++) {
    float4 pa = part[(size_t)s2 * BHW + idx0];
    float4 pb = part[(size_t)s2 * BHW + idx0 + 1];
    Za += pa.x; nHa += pa.y; nWa += pa.z;
    Zb += pb.x; nHb += pb.y; nWb += pb.z;
  }
  float g = gamma[0];
  float2 sv = make_float2(g * (nHa + nWa) / Za, g * (nHb + nWb) / Zb);
  int b = idx0 >> 16, hw = idx0 & (HW - 1);
  size_t base = (size_t)b * Cch * HW + hw;
#pragma unroll
  for (int c = 0; c < Cch; c++) {
    float2 xv = *(const float2*)&x[base + c * HW];
    *(float2*)&out[base + c * HW] = make_float2(sv.x + xv.x, sv.y + xv.y);
  }
}

extern "C" void kernel_launch(void* const* d_in, const int* in_sizes, int n_in,
                              void* d_out, int out_size, void* d_ws, size_t ws_size,
                              hipStream_t stream) {
  const float* x     = (const float*)d_in[0];
  const float* y     = (const float*)d_in[1];
  const float* Wq    = (const float*)d_in[2];
  const float* bq    = (const float*)d_in[3];
  const float* Wk    = (const float*)d_in[4];
  const float* bk    = (const float*)d_in[5];
  const float* Wv    = (const float*)d_in[6];
  const float* bv    = (const float*)d_in[7];
  const float* gamma = (const float*)d_in[8];
  float* out = (float*)d_out;

  float* ws = (float*)d_ws;
  float2* qpk = (float2*)ws;                  // BHW float2 (1 MB)
  float4* kv  = (float4*)(ws + 2 * BHW);      // BHW float4 (2 MB)
  float4* part = (float4*)(ws + 6 * BHW);     // NS*BHW float4 (8.4 MB)

  qkv_kernel<<<BHW / 512, 256, 0, stream>>>(x, y, Wq, bq, Wk, bk, Wv, bv, qpk, kv);
  attn_kernel<<<Bsz * (Hdim / TH) * NS, 256, 0, stream>>>(qpk, kv, part);
  epi_kernel<<<BHW / 512, 256, 0, stream>>>(x, part, gamma, out);
}